// Round 9
// baseline (123.791 us; speedup 1.0000x reference)
//
#include <hip/hip_runtime.h>
#include <hip/hip_bf16.h>

#define NS_TOT 2000
#define NA 1000
#define NI 5
#define NH 32
#define W2LD 40                    // sW2T leading dim (80B rows, bank-spread)

typedef __attribute__((ext_vector_type(2)))  float f32x2;
typedef __attribute__((ext_vector_type(8)))  short short8;   // 8 bf16 = 4 VGPR
typedef __attribute__((ext_vector_type(16))) float f32x16;   // MFMA 32x32 acc

struct f4pair  { f32x2 a, b; };
struct accpair { f32x2 p[8]; };

// Packed Pade[5/4] tanh, paired reciprocal (R15/R17/R18, passing: 0.015625).
__device__ __forceinline__ f32x2 tanh_pk(f32x2 X) {
    f32x2 z = X * X;
    f32x2 n = (z + 105.0f) * z + 945.0f;
    f32x2 d = (z * 15.0f + 420.0f) * z + 945.0f;
    const float rr = __builtin_amdgcn_rcpf(d.x * d.y);
    f32x2 r;
    r.x = rr * d.y;
    r.y = rr * d.x;
    f32x2 t = X * n * r;
    t.x = __builtin_amdgcn_fmed3f(t.x, -1.0f, 1.0f);
    t.y = __builtin_amdgcn_fmed3f(t.y, -1.0f, 1.0f);
    return t;
}

__device__ __forceinline__ unsigned short f2bf_rne(float x) {
    unsigned u = __float_as_uint(x);
    unsigned r = u + 0x7FFFu + ((u >> 16) & 1u);
    return (unsigned short)(r >> 16);
}
__device__ __forceinline__ unsigned pack2(float a, float b) {
    __hip_bfloat162 p = __float22bfloat162_rn(make_float2(a, b));
    unsigned u; __builtin_memcpy(&u, &p, 4); return u;
}
__device__ __forceinline__ unsigned tanh2_pack(float a, float b) {
    f32x2 X = {a, b};
    f32x2 t = tanh_pk(X);
    return pack2(t.x, t.y);
}

// R19: R13/R14 best structure (bit-identical per-struct math: hoisted b2acc
// and w3 fragments, packed tanh, pair-rcp, 2-ahead prefetch, NO fences) with
// GEOMETRY ONLY changed: 512-thread blocks (8 waves), 1000 blocks (one per
// atom, all 2000 structs). Rationale: OccupancyPercent is pinned at 25-31%
// (~2.4 WGs/CU) across every VGPR/LDS/waves_per_eu configuration tried --
// consistent with a per-CU workgroup-residency cap, which would explain why
// both extra wave-slots (R13) and in-wave ILP (R18, serialized by regalloc
// to VGPR=72) returned nothing. 8-wave WGs double resident waves/SIMD under
// a fixed WG/CU cap. Bonus: each atom's weights staged once (not twice),
// half the blocks (no dispatch tail).
__global__ __attribute__((amdgpu_flat_work_group_size(512, 512),
                          amdgpu_waves_per_eu(4, 8)))
void mlp_mfma(
    const float* __restrict__ g,
    const float* __restrict__ W1, const float* __restrict__ b1,
    const float* __restrict__ W2, const float* __restrict__ b2,
    const float* __restrict__ W3, const float* __restrict__ b3,
    float* __restrict__ out)
{
    const int bid = blockIdx.x;
    const int a = (bid >> 3) + 125 * (bid & 7);     // same-XCD atom swizzle
    const int t = threadIdx.x;
    const int lane = t & 63, wid = t >> 6;          // wid in [0,8)
    const int l31 = lane & 31, half = lane >> 5;

    __shared__ __align__(16) unsigned short sW2T[NH * W2LD];  // W2^T bf16 [m][k]
    __shared__ __align__(16) unsigned short sW1T[NH * 8];     // [m]{W1[0..4][m],b1[m],0,0}
    __shared__ __align__(16) float sB2[NH];
    __shared__ __align__(16) float sW3[NH];

    for (int idx = t; idx < NH * NH; idx += 512) {
        const int i = idx >> 5, j = idx & 31;       // i = k row of W2, j = m col
        sW2T[j * W2LD + i] = f2bf_rne(W2[(size_t)a * NH * NH + idx]);
    }
    if (t < NH) {
        sB2[t] = b2[a * NH + t];
        sW3[t] = W3[a * NH + t];
        const int m = t;
        #pragma unroll
        for (int i = 0; i < NI; ++i)
            sW1T[m * 8 + i] = f2bf_rne(W1[(size_t)a * NI * NH + i * NH + m]);
        sW1T[m * 8 + 5] = f2bf_rne(b1[a * NH + m]);
        sW1T[m * 8 + 6] = 0;
        sW1T[m * 8 + 7] = 0;
    }
    __syncthreads();

    // persistent fragments (hoisted once per block)
    const short8 zero8 = {0,0,0,0,0,0,0,0};
    const short8 w1ld = __builtin_bit_cast(short8, *(const uint4*)(sW1T + l31 * 8));
    const short8 afl1 = half ? zero8 : w1ld;   // A[m][k]: half1 = K-pad zeros
    const short8 af0 = __builtin_bit_cast(short8, *(const uint4*)(sW2T + l31 * W2LD + half * 8));
    const short8 af1 = __builtin_bit_cast(short8, *(const uint4*)(sW2T + l31 * W2LD + 16 + half * 8));
    const float4 b2q0 = ((const float4*)sB2)[0 + half];
    const float4 b2q1 = ((const float4*)sB2)[2 + half];
    const float4 b2q2 = ((const float4*)sB2)[4 + half];
    const float4 b2q3 = ((const float4*)sB2)[6 + half];
    const f4pair w3p0 = __builtin_bit_cast(f4pair, ((const float4*)sW3)[0 + half]);
    const f4pair w3p1 = __builtin_bit_cast(f4pair, ((const float4*)sW3)[2 + half]);
    const f4pair w3p2 = __builtin_bit_cast(f4pair, ((const float4*)sW3)[4 + half]);
    const f4pair w3p3 = __builtin_bit_cast(f4pair, ((const float4*)sW3)[6 + half]);
    const float bias3 = b3[a];
    const f32x16 zacc = {0,0,0,0,0,0,0,0,0,0,0,0,0,0,0,0};
    const f32x16 b2acc = {b2q0.x, b2q0.y, b2q0.z, b2q0.w,
                          b2q1.x, b2q1.y, b2q1.z, b2q1.w,
                          b2q2.x, b2q2.y, b2q2.z, b2q2.w,
                          b2q3.x, b2q3.y, b2q3.z, b2q3.w};

    // prologue: g for it=0 (x*) and it=1 (y*)
    float x0g, x1g, x2g, x3g, x4g;
    float y0g, y1g, y2g, y3g, y4g;
    {
        const int s0 = wid * 64 + lane;             // < 512, always valid
        const float* gp = g + ((size_t)s0 * NA + a) * NI;
        x0g = gp[0]; x1g = gp[1]; x2g = gp[2]; x3g = gp[3]; x4g = gp[4];
        const int s1 = s0 + 512;                    // < 1024, always valid
        const float* gq = g + ((size_t)s1 * NA + a) * NI;
        y0g = gq[0]; y1g = gq[1]; y2g = gq[2]; y3g = gq[3]; y4g = gq[4];
    }

    #pragma unroll
    for (int it = 0; it < 4; ++it) {
        const int s = it * 512 + wid * 64 + lane;   // [0, 2048), mask at store

        // ---- prefetch it+2's row under this iteration's compute ----
        float n0, n1, n2, n3, n4;
        if (it < 2) {
            const int sn = s + 1024;
            const int sln = (sn < NS_TOT) ? sn : (NS_TOT - 1);
            const float* gq = g + ((size_t)sln * NA + a) * NI;
            n0 = gq[0]; n1 = gq[1]; n2 = gq[2]; n3 = gq[3]; n4 = gq[4];
        }

        // ---- build g B-fragments (K slots: g0..g4, 1.0(bias), X, X) ----
        // Half-1 words feed A's zeroed k=8..15 -> garbage * 0.0 = 0.
        const unsigned gp01 = pack2(x0g, x1g);
        const unsigned gp23 = pack2(x2g, x3g);
        const unsigned gp45 = pack2(x4g, 1.0f);
        auto gs01 = __builtin_amdgcn_permlane32_swap(gp01, gp01, false, false);
        auto gs23 = __builtin_amdgcn_permlane32_swap(gp23, gp23, false, false);
        auto gs45 = __builtin_amdgcn_permlane32_swap(gp45, gp45, false, false);
        const short8 gb0 = __builtin_bit_cast(short8, make_uint4(gp01, gp23, gp45, 0u));
        const short8 gb1 = __builtin_bit_cast(short8, make_uint4(gs01[1], gs23[1], gs45[1], 0u));

        // ---- layer 1 via MFMA (bias folded in) ----
        f32x16 d0 = __builtin_amdgcn_mfma_f32_32x32x16_bf16(afl1, gb0, zacc, 0, 0, 0);
        f32x16 d1 = __builtin_amdgcn_mfma_f32_32x32x16_bf16(afl1, gb1, zacc, 0, 0, 0);

        // ---- mid-layer: packed tanh + cvt_pk, permlane32_swap C->B ----
        // C row of reg r = (r&3) + 8*(r>>2) + 4*half. swap(a,b).x = {a_lo,b_lo},
        // .y = {a_hi,b_hi}: exactly B-frag words (k = half*8 + 2w, 2w+1).
        short8 bk0_0, bk1_0, bk0_1, bk1_1;
        #define TILE_CONV(DD, BK0, BK1) { \
            const unsigned p0 = tanh2_pack(DD[0],  DD[1]); \
            const unsigned p1 = tanh2_pack(DD[2],  DD[3]); \
            const unsigned p2 = tanh2_pack(DD[4],  DD[5]); \
            const unsigned p3 = tanh2_pack(DD[6],  DD[7]); \
            const unsigned p4 = tanh2_pack(DD[8],  DD[9]); \
            const unsigned p5 = tanh2_pack(DD[10], DD[11]); \
            const unsigned p6 = tanh2_pack(DD[12], DD[13]); \
            const unsigned p7 = tanh2_pack(DD[14], DD[15]); \
            auto s02 = __builtin_amdgcn_permlane32_swap(p0, p2, false, false); \
            auto s13 = __builtin_amdgcn_permlane32_swap(p1, p3, false, false); \
            auto s46 = __builtin_amdgcn_permlane32_swap(p4, p6, false, false); \
            auto s57 = __builtin_amdgcn_permlane32_swap(p5, p7, false, false); \
            BK0 = __builtin_bit_cast(short8, make_uint4(s02[0], s13[0], s02[1], s13[1])); \
            BK1 = __builtin_bit_cast(short8, make_uint4(s46[0], s57[0], s46[1], s57[1])); }
        TILE_CONV(d0, bk0_0, bk1_0)
        TILE_CONV(d1, bk0_1, bk1_1)
        #undef TILE_CONV

        // ---- layer 2 MFMA (bias via persistent b2acc) ----
        f32x16 acc0 = __builtin_amdgcn_mfma_f32_32x32x16_bf16(af0, bk0_0, b2acc, 0, 0, 0);
        acc0 = __builtin_amdgcn_mfma_f32_32x32x16_bf16(af1, bk1_0, acc0, 0, 0, 0);
        f32x16 acc1 = __builtin_amdgcn_mfma_f32_32x32x16_bf16(af0, bk0_1, b2acc, 0, 0, 0);
        acc1 = __builtin_amdgcn_mfma_f32_32x32x16_bf16(af1, bk1_1, acc1, 0, 0, 0);

        // ---- epilogue: acc0 fully, then acc1 (early reg release) ----
        const accpair ap0 = __builtin_bit_cast(accpair, acc0);
        f32x2 p0 = {0.f, 0.f};
        p0 += tanh_pk(ap0.p[0]) * w3p0.a;  p0 += tanh_pk(ap0.p[1]) * w3p0.b;
        p0 += tanh_pk(ap0.p[2]) * w3p1.a;  p0 += tanh_pk(ap0.p[3]) * w3p1.b;
        p0 += tanh_pk(ap0.p[4]) * w3p2.a;  p0 += tanh_pk(ap0.p[5]) * w3p2.b;
        p0 += tanh_pk(ap0.p[6]) * w3p3.a;  p0 += tanh_pk(ap0.p[7]) * w3p3.b;
        const float e0 = p0.x + p0.y;
        const accpair ap1 = __builtin_bit_cast(accpair, acc1);
        f32x2 p1 = {0.f, 0.f};
        p1 += tanh_pk(ap1.p[0]) * w3p0.a;  p1 += tanh_pk(ap1.p[1]) * w3p0.b;
        p1 += tanh_pk(ap1.p[2]) * w3p1.a;  p1 += tanh_pk(ap1.p[3]) * w3p1.b;
        p1 += tanh_pk(ap1.p[4]) * w3p2.a;  p1 += tanh_pk(ap1.p[5]) * w3p2.b;
        p1 += tanh_pk(ap1.p[6]) * w3p3.a;  p1 += tanh_pk(ap1.p[7]) * w3p3.b;
        const float e1 = p1.x + p1.y;
        // One swap fuses both cross-half reductions; every lane stores its
        // own struct: half0 lane l -> e0 sum (struct base+l), half1 -> e1.
        auto es = __builtin_amdgcn_permlane32_swap(__float_as_uint(e0),
                                                   __float_as_uint(e1),
                                                   false, false);
        const float etot = __uint_as_float(es[0]) + __uint_as_float(es[1]);
        if (s < NS_TOT) out[(size_t)s * NA + a] = etot + bias3;

        // rotate prefetched rows
        if (it < 3) { x0g = y0g; x1g = y1g; x2g = y2g; x3g = y3g; x4g = y4g; }
        if (it < 2) { y0g = n0; y1g = n1; y2g = n2; y3g = n3; y4g = n4; }
    }
}

extern "C" void kernel_launch(void* const* d_in, const int* in_sizes, int n_in,
                              void* d_out, int out_size, void* d_ws, size_t ws_size,
                              hipStream_t stream) {
    const float* g  = (const float*)d_in[0];
    const float* W1 = (const float*)d_in[1];
    const float* b1 = (const float*)d_in[2];
    const float* W2 = (const float*)d_in[3];
    const float* b2 = (const float*)d_in[4];
    const float* W3 = (const float*)d_in[5];
    const float* b3 = (const float*)d_in[6];
    float* out = (float*)d_out;
    mlp_mfma<<<dim3(NA), dim3(512), 0, stream>>>(g, W1, b1, W2, b2, W3, b3, out);
}

// Round 10
// 113.195 us; speedup vs baseline: 1.0936x; 1.0936x over previous
//
#include <hip/hip_runtime.h>
#include <hip/hip_bf16.h>

#define NS_TOT 2000
#define NA 1000
#define NI 5
#define NH 32
#define SHALF 1000                 // structs per block (two blocks per atom)
#define W2LD 40                    // sW2T leading dim (80B rows, bank-spread)

typedef __attribute__((ext_vector_type(2)))  float f32x2;
typedef __attribute__((ext_vector_type(8)))  short short8;   // 8 bf16 = 4 VGPR
typedef __attribute__((ext_vector_type(16))) float f32x16;   // MFMA 32x32 acc

struct f4pair  { f32x2 a, b; };
struct accpair { f32x2 p[8]; };

// R20: tanh via the HARDWARE exp unit instead of Pade polynomials.
// tanh(x) = 1 - 2/(e^{2x}+1) = 1 - 2*r,  r = 1/(E+1), E = exp2(2*log2e*x).
// Per pair: 1 pk_mul + 2 v_exp_f32 + 1 pk_add + paired-rcp(3V+1T) + 1 pk_fma
// = 7 VALU + 3 TRANS, vs Pade's 13 VALU + 1 TRANS. Moves ~40% of the VALU
// work onto the (idle) transcendental pipe. More accurate than Pade (~1e-6),
// saturates gracefully (E overflow -> rr=0 -> t=1 exact), no clamps needed.
__device__ __forceinline__ f32x2 sigr_pk(f32x2 X) {
    const f32x2 a = X * 2.8853900817779268f;     // 2*log2(e)
    f32x2 E;
    E.x = __builtin_amdgcn_exp2f(a.x);
    E.y = __builtin_amdgcn_exp2f(a.y);
    const f32x2 D = E + 1.0f;
    const float rr = __builtin_amdgcn_rcpf(D.x * D.y);  // paired reciprocal
    f32x2 r;
    r.x = rr * D.y;
    r.y = rr * D.x;
    return r;
}
__device__ __forceinline__ f32x2 tanh_pk(f32x2 X) {
    const f32x2 r = sigr_pk(X);
    return r * (-2.0f) + 1.0f;                   // pk_fma
}

__device__ __forceinline__ unsigned short f2bf_rne(float x) {
    unsigned u = __float_as_uint(x);
    unsigned r = u + 0x7FFFu + ((u >> 16) & 1u);
    return (unsigned short)(r >> 16);
}
__device__ __forceinline__ unsigned pack2(float a, float b) {
    __hip_bfloat162 p = __float22bfloat162_rn(make_float2(a, b));
    unsigned u; __builtin_memcpy(&u, &p, 4); return u;
}
__device__ __forceinline__ unsigned tanh2_pack(float a, float b) {
    f32x2 X = {a, b};
    f32x2 t = tanh_pk(X);
    return pack2(t.x, t.y);
}

// Host structure = R14 verbatim (best measured 45.5us: pipelined source
// order, NO fences, hoisted b2acc/w3, 2-ahead prefetch). Epilogue folds the
// layer-3 dot algebraically: sum(t*w) = sum(w) - 2*sum(r*w), with per-lane
// wsum precomputed once per block -- drops the t-reconstruction fma AND the
// clamps from all 32 epilogue tanh evaluations.
__global__ __attribute__((amdgpu_flat_work_group_size(256, 256),
                          amdgpu_waves_per_eu(3, 4)))
void mlp_mfma(
    const float* __restrict__ g,
    const float* __restrict__ W1, const float* __restrict__ b1,
    const float* __restrict__ W2, const float* __restrict__ b2,
    const float* __restrict__ W3, const float* __restrict__ b3,
    float* __restrict__ out)
{
    const int bid   = blockIdx.x;
    const int araw  = bid % NA;
    const int chunk = bid / NA;
    const int a = (araw >> 3) + 125 * (araw & 7);   // same-XCD atom swizzle
    const int t = threadIdx.x;
    const int lane = t & 63, wid = t >> 6;
    const int l31 = lane & 31, half = lane >> 5;

    const int sbase_blk = chunk * SHALF;
    const int send      = sbase_blk + SHALF;

    __shared__ __align__(16) unsigned short sW2T[NH * W2LD];  // W2^T bf16 [m][k]
    __shared__ __align__(16) unsigned short sW1T[NH * 8];     // [m]{W1[0..4][m],b1[m],0,0}
    __shared__ __align__(16) float sB2[NH];
    __shared__ __align__(16) float sW3[NH];

    for (int idx = t; idx < NH * NH; idx += 256) {
        const int i = idx >> 5, j = idx & 31;       // i = k row of W2, j = m col
        sW2T[j * W2LD + i] = f2bf_rne(W2[(size_t)a * NH * NH + idx]);
    }
    if (t < NH) {
        sB2[t] = b2[a * NH + t];
        sW3[t] = W3[a * NH + t];
        const int m = t;
        #pragma unroll
        for (int i = 0; i < NI; ++i)
            sW1T[m * 8 + i] = f2bf_rne(W1[(size_t)a * NI * NH + i * NH + m]);
        sW1T[m * 8 + 5] = f2bf_rne(b1[a * NH + m]);
        sW1T[m * 8 + 6] = 0;
        sW1T[m * 8 + 7] = 0;
    }
    __syncthreads();

    // persistent fragments
    const short8 zero8 = {0,0,0,0,0,0,0,0};
    const short8 w1ld = __builtin_bit_cast(short8, *(const uint4*)(sW1T + l31 * 8));
    const short8 afl1 = half ? zero8 : w1ld;   // A[m][k]: half1 = K-pad zeros
    const short8 af0 = __builtin_bit_cast(short8, *(const uint4*)(sW2T + l31 * W2LD + half * 8));
    const short8 af1 = __builtin_bit_cast(short8, *(const uint4*)(sW2T + l31 * W2LD + 16 + half * 8));
    const float4 b2q0 = ((const float4*)sB2)[0 + half];
    const float4 b2q1 = ((const float4*)sB2)[2 + half];
    const float4 b2q2 = ((const float4*)sB2)[4 + half];
    const float4 b2q3 = ((const float4*)sB2)[6 + half];
    const f4pair w3p0 = __builtin_bit_cast(f4pair, ((const float4*)sW3)[0 + half]);
    const f4pair w3p1 = __builtin_bit_cast(f4pair, ((const float4*)sW3)[2 + half]);
    const f4pair w3p2 = __builtin_bit_cast(f4pair, ((const float4*)sW3)[4 + half]);
    const f4pair w3p3 = __builtin_bit_cast(f4pair, ((const float4*)sW3)[6 + half]);
    // per-lane sum of this lane's 16 w3 values (for sum(t*w) folding)
    const f32x2 ws2 = w3p0.a + w3p0.b + w3p1.a + w3p1.b
                    + w3p2.a + w3p2.b + w3p3.a + w3p3.b;
    const float wsum = ws2.x + ws2.y;
    const float bias3 = b3[a];
    const f32x16 zacc = {0,0,0,0,0,0,0,0,0,0,0,0,0,0,0,0};
    const f32x16 b2acc = {b2q0.x, b2q0.y, b2q0.z, b2q0.w,
                          b2q1.x, b2q1.y, b2q1.z, b2q1.w,
                          b2q2.x, b2q2.y, b2q2.z, b2q2.w,
                          b2q3.x, b2q3.y, b2q3.z, b2q3.w};

    // g-frag build + L1 MFMAs (K slots: g0..g4, 1.0(bias), X, X; half-1
    // garbage words feed A's zeroed k=8..15 -> x*0 = 0, no masking).
    #define BUILD_L1(AX0, AX1, AX2, AX3, AX4) { \
        const unsigned gp01 = pack2(AX0, AX1); \
        const unsigned gp23 = pack2(AX2, AX3); \
        const unsigned gp45 = pack2(AX4, 1.0f); \
        auto gs01 = __builtin_amdgcn_permlane32_swap(gp01, gp01, false, false); \
        auto gs23 = __builtin_amdgcn_permlane32_swap(gp23, gp23, false, false); \
        auto gs45 = __builtin_amdgcn_permlane32_swap(gp45, gp45, false, false); \
        const uint4 bu0 = make_uint4(gp01,    gp23,    gp45,    0u); \
        const uint4 bu1 = make_uint4(gs01[1], gs23[1], gs45[1], 0u); \
        const short8 gb0 = __builtin_bit_cast(short8, bu0); \
        const short8 gb1 = __builtin_bit_cast(short8, bu1); \
        d0 = __builtin_amdgcn_mfma_f32_32x32x16_bf16(afl1, gb0, zacc, 0, 0, 0); \
        d1 = __builtin_amdgcn_mfma_f32_32x32x16_bf16(afl1, gb1, zacc, 0, 0, 0); }

    // prologue: g for it=0 (x*) and it=1 (y*); front-end of it=0.
    float x0g, x1g, x2g, x3g, x4g;
    float y0g, y1g, y2g, y3g, y4g;
    {
        const int s0 = sbase_blk + wid * 64 + lane;
        const float* gp = g + ((size_t)s0 * NA + a) * NI;
        x0g = gp[0]; x1g = gp[1]; x2g = gp[2]; x3g = gp[3]; x4g = gp[4];
        const int s1 = s0 + 256;                       // always < send for it=1
        const float* gq = g + ((size_t)s1 * NA + a) * NI;
        y0g = gq[0]; y1g = gq[1]; y2g = gq[2]; y3g = gq[3]; y4g = gq[4];
    }
    f32x16 d0, d1;
    BUILD_L1(x0g, x1g, x2g, x3g, x4g)

    #pragma unroll
    for (int it = 0; it < 4; ++it) {
        const int base = sbase_blk + it * 256 + wid * 64;
        const int s = base + lane;

        // ---- mid-layer: exp-tanh + cvt_pk, permlane32_swap C->B ----
        // C row of reg r = (r&3) + 8*(r>>2) + 4*half. swap(a,b).x = {a_lo,b_lo},
        // .y = {a_hi,b_hi}: exactly B-frag words (k = half*8 + 2w, 2w+1).
        short8 bk0_0, bk1_0, bk0_1, bk1_1;
        #define TILE_CONV(DD, BK0, BK1) { \
            const unsigned p0 = tanh2_pack(DD[0],  DD[1]); \
            const unsigned p1 = tanh2_pack(DD[2],  DD[3]); \
            const unsigned p2 = tanh2_pack(DD[4],  DD[5]); \
            const unsigned p3 = tanh2_pack(DD[6],  DD[7]); \
            const unsigned p4 = tanh2_pack(DD[8],  DD[9]); \
            const unsigned p5 = tanh2_pack(DD[10], DD[11]); \
            const unsigned p6 = tanh2_pack(DD[12], DD[13]); \
            const unsigned p7 = tanh2_pack(DD[14], DD[15]); \
            auto s02 = __builtin_amdgcn_permlane32_swap(p0, p2, false, false); \
            auto s13 = __builtin_amdgcn_permlane32_swap(p1, p3, false, false); \
            auto s46 = __builtin_amdgcn_permlane32_swap(p4, p6, false, false); \
            auto s57 = __builtin_amdgcn_permlane32_swap(p5, p7, false, false); \
            BK0 = __builtin_bit_cast(short8, make_uint4(s02[0], s13[0], s02[1], s13[1])); \
            BK1 = __builtin_bit_cast(short8, make_uint4(s46[0], s57[0], s46[1], s57[1])); }
        TILE_CONV(d0, bk0_0, bk1_0)
        TILE_CONV(d1, bk0_1, bk1_1)
        #undef TILE_CONV

        // ---- next-iter front-end (source-pipelined; scheduler may place) ----
        if (it < 3) {
            BUILD_L1(y0g, y1g, y2g, y3g, y4g)
        }

        // ---- layer 2 MFMA (bias via persistent b2acc) ----
        f32x16 acc0 = __builtin_amdgcn_mfma_f32_32x32x16_bf16(af0, bk0_0, b2acc, 0, 0, 0);
        acc0 = __builtin_amdgcn_mfma_f32_32x32x16_bf16(af1, bk1_0, acc0, 0, 0, 0);
        f32x16 acc1 = __builtin_amdgcn_mfma_f32_32x32x16_bf16(af0, bk0_1, b2acc, 0, 0, 0);
        acc1 = __builtin_amdgcn_mfma_f32_32x32x16_bf16(af1, bk1_1, acc1, 0, 0, 0);

        // refill y* for it+2
        if (it < 2) {
            const int sn = s + 512;
            const int sln = (sn < send) ? sn : (send - 1);
            const float* gq = g + ((size_t)sln * NA + a) * NI;
            y0g = gq[0]; y1g = gq[1]; y2g = gq[2]; y3g = gq[3]; y4g = gq[4];
        }

        // ---- epilogue: folded dot  e = wsum - 2*sum(r*w)  (acc0 then acc1) ----
        const accpair ap0 = __builtin_bit_cast(accpair, acc0);
        f32x2 p0 = {0.f, 0.f};
        p0 += sigr_pk(ap0.p[0]) * w3p0.a;  p0 += sigr_pk(ap0.p[1]) * w3p0.b;
        p0 += sigr_pk(ap0.p[2]) * w3p1.a;  p0 += sigr_pk(ap0.p[3]) * w3p1.b;
        p0 += sigr_pk(ap0.p[4]) * w3p2.a;  p0 += sigr_pk(ap0.p[5]) * w3p2.b;
        p0 += sigr_pk(ap0.p[6]) * w3p3.a;  p0 += sigr_pk(ap0.p[7]) * w3p3.b;
        const float e0 = fmaf(-2.0f, p0.x + p0.y, wsum);
        const accpair ap1 = __builtin_bit_cast(accpair, acc1);
        f32x2 p1 = {0.f, 0.f};
        p1 += sigr_pk(ap1.p[0]) * w3p0.a;  p1 += sigr_pk(ap1.p[1]) * w3p0.b;
        p1 += sigr_pk(ap1.p[2]) * w3p1.a;  p1 += sigr_pk(ap1.p[3]) * w3p1.b;
        p1 += sigr_pk(ap1.p[4]) * w3p2.a;  p1 += sigr_pk(ap1.p[5]) * w3p2.b;
        p1 += sigr_pk(ap1.p[6]) * w3p3.a;  p1 += sigr_pk(ap1.p[7]) * w3p3.b;
        const float e1 = fmaf(-2.0f, p1.x + p1.y, wsum);
        // One swap fuses both cross-half reductions; every lane stores its
        // own struct: half0 lane l -> e0 sum (struct base+l), half1 -> e1.
        auto es = __builtin_amdgcn_permlane32_swap(__float_as_uint(e0),
                                                   __float_as_uint(e1),
                                                   false, false);
        const float etot = __uint_as_float(es[0]) + __uint_as_float(es[1]);
        if (s < send) out[(size_t)s * NA + a] = etot + bias3;
    }
    #undef BUILD_L1
}

extern "C" void kernel_launch(void* const* d_in, const int* in_sizes, int n_in,
                              void* d_out, int out_size, void* d_ws, size_t ws_size,
                              hipStream_t stream) {
    const float* g  = (const float*)d_in[0];
    const float* W1 = (const float*)d_in[1];
    const float* b1 = (const float*)d_in[2];
    const float* W2 = (const float*)d_in[3];
    const float* b2 = (const float*)d_in[4];
    const float* W3 = (const float*)d_in[5];
    const float* b3 = (const float*)d_in[6];
    float* out = (float*)d_out;
    mlp_mfma<<<dim3(NA * 2), dim3(256), 0, stream>>>(g, W1, b1, W2, b2, W3, b3, out);
}